// Round 3
// baseline (5400.340 us; speedup 1.0000x reference)
//
#include <hip/hip_runtime.h>
#include <math.h>

constexpr int N_NODES = 500000;
constexpr int N_EDGES = 8000000;
constexpr int IN_DIM = 10, HID_DIM = 35, OUT_DIM = 2;

// Hardware FP32 global atomic (global_atomic_add_f32). Values are O(1) floats,
// denormal-flush semantics irrelevant at our tolerance.
__device__ __forceinline__ void atomAddF(float* p, float v) {
    unsafeAtomicAdd(p, v);
}

// ---------------- init: deg=0, zero aggX/agg2 ----------------
__global__ void init_kernel(unsigned* __restrict__ deg, float* __restrict__ aggX,
                            float* __restrict__ agg2, int N) {
    int stride = gridDim.x * blockDim.x;
    for (int i = blockIdx.x * blockDim.x + threadIdx.x; i < N; i += stride) {
        deg[i] = 0u;
        #pragma unroll
        for (int k = 0; k < IN_DIM; ++k) aggX[(size_t)i * IN_DIM + k] = 0.0f;
        reinterpret_cast<float2*>(agg2)[i] = make_float2(0.0f, 0.0f);
    }
}

// ---------------- degree: deg[dst] += 1 (int atomics) ----------------
__global__ void degree_kernel(const int* __restrict__ dst, unsigned* __restrict__ deg, int E) {
    int stride = gridDim.x * blockDim.x;
    for (int e = blockIdx.x * blockDim.x + threadIdx.x; e < E; e += stride) {
        atomicAdd(&deg[dst[e]], 1u);
    }
}

// ---------------- dinv = rsqrt(deg+1); prescale x in place: x[i] *= dinv[i] ----
// (legal: harness restores d_in from pristine before every timed launch)
__global__ void dinv_scale_kernel(const unsigned* __restrict__ deg, float* __restrict__ dinv,
                                  float* __restrict__ x, int N) {
    int stride = gridDim.x * blockDim.x;
    for (int i = blockIdx.x * blockDim.x + threadIdx.x; i < N; i += stride) {
        float di = rsqrtf((float)deg[i] + 1.0f);  // +1 = self-loop
        dinv[i] = di;
        float* xr = x + (size_t)i * IN_DIM;
        #pragma unroll
        for (int k = 0; k < IN_DIM; ++k) xr[k] *= di;
    }
}

// ---------------- layer-1 aggregation in 10-dim input space ----------------
// aggX[dst] += xs[src]   (xs already prescaled by dinv[src]; dinv[dst] applied later)
__global__ void aggx_kernel(const int* __restrict__ src, const int* __restrict__ dst,
                            const float* __restrict__ xs, float* __restrict__ aggX, int E) {
    int stride = gridDim.x * blockDim.x;
    for (int e = blockIdx.x * blockDim.x + threadIdx.x; e < E; e += stride) {
        int s = src[e];
        int d = dst[e];
        const float2* xr = reinterpret_cast<const float2*>(xs + (size_t)s * IN_DIM);
        float* ar = aggX + (size_t)d * IN_DIM;
        #pragma unroll
        for (int k = 0; k < IN_DIM / 2; ++k) {
            float2 v = xr[k];
            atomAddF(ar + 2 * k + 0, v.x);
            atomAddF(ar + 2 * k + 1, v.y);
        }
    }
}

// ---------------- fused node transform ----------------
// v = dinv[i]*(aggX[i] + xs[i])        (xs = x*dinv, so dinv*xs = dinv^2*x self-loop)
// h = relu(v @ W1 + b1)                (35, registers)
// ts[i] = dinv[i] * (h @ W2)           ([N,2]; prescaled for layer-2 aggregation)
__global__ void node_kernel(const float* __restrict__ xs, const float* __restrict__ aggX,
                            const float* __restrict__ dinv,
                            const float* __restrict__ W1, const float* __restrict__ b1,
                            const float* __restrict__ W2,
                            float* __restrict__ ts, int N) {
    __shared__ float sW1[IN_DIM * HID_DIM];
    __shared__ float sb1[HID_DIM];
    __shared__ float sW2[HID_DIM * OUT_DIM];
    for (int k = threadIdx.x; k < IN_DIM * HID_DIM; k += blockDim.x) sW1[k] = W1[k];
    for (int k = threadIdx.x; k < HID_DIM; k += blockDim.x) sb1[k] = b1[k];
    for (int k = threadIdx.x; k < HID_DIM * OUT_DIM; k += blockDim.x) sW2[k] = W2[k];
    __syncthreads();

    int stride = gridDim.x * blockDim.x;
    for (int i = blockIdx.x * blockDim.x + threadIdx.x; i < N; i += stride) {
        float di = dinv[i];
        float v[IN_DIM];
        #pragma unroll
        for (int k = 0; k < IN_DIM; ++k)
            v[k] = di * (aggX[(size_t)i * IN_DIM + k] + xs[(size_t)i * IN_DIM + k]);
        float t0 = 0.0f, t1 = 0.0f;
        #pragma unroll
        for (int j = 0; j < HID_DIM; ++j) {
            float h = sb1[j];
            #pragma unroll
            for (int k = 0; k < IN_DIM; ++k) h = fmaf(v[k], sW1[k * HID_DIM + j], h);
            h = fmaxf(h, 0.0f);
            t0 = fmaf(h, sW2[j * OUT_DIM + 0], t0);
            t1 = fmaf(h, sW2[j * OUT_DIM + 1], t1);
        }
        reinterpret_cast<float2*>(ts)[i] = make_float2(t0 * di, t1 * di);
    }
}

// ---------------- layer-2 aggregation in 2-dim output space ----------------
// agg2[dst] += ts[src]   (ts prescaled by dinv[src])
__global__ void agg2_kernel(const int* __restrict__ src, const int* __restrict__ dst,
                            const float* __restrict__ ts, float* __restrict__ agg2, int E) {
    int stride = gridDim.x * blockDim.x;
    for (int e = blockIdx.x * blockDim.x + threadIdx.x; e < E; e += stride) {
        int s = src[e];
        int d = dst[e];
        float2 tv = reinterpret_cast<const float2*>(ts)[s];
        atomAddF(&agg2[(size_t)d * 2 + 0], tv.x);
        atomAddF(&agg2[(size_t)d * 2 + 1], tv.y);
    }
}

// ---------------- epilogue: norm + self-loop + bias + log_softmax(2) ----------
// a = dinv[i]*(agg2[i] + ts[i]) + b2
__global__ void final_kernel(const float* __restrict__ agg2, const float* __restrict__ ts,
                             const float* __restrict__ dinv, const float* __restrict__ b2,
                             float* __restrict__ out, int N) {
    float b20 = b2[0], b21 = b2[1];
    int stride = gridDim.x * blockDim.x;
    for (int i = blockIdx.x * blockDim.x + threadIdx.x; i < N; i += stride) {
        float di = dinv[i];
        float2 tv = reinterpret_cast<const float2*>(ts)[i];
        float2 ag = reinterpret_cast<const float2*>(agg2)[i];
        float a0 = di * (ag.x + tv.x) + b20;
        float a1 = di * (ag.y + tv.y) + b21;
        float m = fmaxf(a0, a1);
        float lse = m + logf(expf(a0 - m) + expf(a1 - m));
        reinterpret_cast<float2*>(out)[i] = make_float2(a0 - lse, a1 - lse);
    }
}

extern "C" void kernel_launch(void* const* d_in, const int* in_sizes, int n_in,
                              void* d_out, int out_size, void* d_ws, size_t ws_size,
                              hipStream_t stream) {
    float* x        = (float*)d_in[0];          // mutated in place (restored by harness)
    const int* ei   = (const int*)d_in[1];      // [2, E]: src row then dst row
    const float* W1 = (const float*)d_in[2];
    const float* b1 = (const float*)d_in[3];
    const float* W2 = (const float*)d_in[4];
    const float* b2 = (const float*)d_in[5];
    float* out = (float*)d_out;

    const int* src = ei;
    const int* dst = ei + N_EDGES;

    // workspace (floats): deg[N](as uint) | dinv[N] | aggX[N*10] | ts[N*2] | agg2[N*2]  = 32 MB
    float* ws      = (float*)d_ws;
    unsigned* deg  = (unsigned*)ws;
    float* dinv    = ws + N_NODES;
    float* aggX    = dinv + N_NODES;
    float* ts      = aggX + (size_t)N_NODES * IN_DIM;
    float* agg2    = ts + (size_t)N_NODES * OUT_DIM;

    const int BLK = 256;
    const int node_grid = (N_NODES + BLK - 1) / BLK;  // 1954
    const int edge_grid = 8192;                        // grid-stride over 8M edges

    init_kernel<<<node_grid, BLK, 0, stream>>>(deg, aggX, agg2, N_NODES);
    degree_kernel<<<edge_grid, BLK, 0, stream>>>(dst, deg, N_EDGES);
    dinv_scale_kernel<<<node_grid, BLK, 0, stream>>>(deg, dinv, x, N_NODES);
    aggx_kernel<<<edge_grid, BLK, 0, stream>>>(src, dst, x, aggX, N_EDGES);
    node_kernel<<<node_grid, BLK, 0, stream>>>(x, aggX, dinv, W1, b1, W2, ts, N_NODES);
    agg2_kernel<<<edge_grid, BLK, 0, stream>>>(src, dst, ts, agg2, N_EDGES);
    final_kernel<<<node_grid, BLK, 0, stream>>>(agg2, ts, dinv, b2, out, N_NODES);
}

// Round 4
// 1325.826 us; speedup vs baseline: 4.0732x; 4.0732x over previous
//
#include <hip/hip_runtime.h>
#include <math.h>

constexpr int N_NODES = 500000;
constexpr int N_EDGES = 8000000;
constexpr int IN_DIM = 10, HID_DIM = 35, OUT_DIM = 2;
constexpr int SCAN_ELEMS = 1024;  // per scan block: 256 threads x 4 elems
constexpr int NBLK_SCAN = (N_NODES + SCAN_ELEMS - 1) / SCAN_ELEMS;  // 489 (<512)

// ---------------- zero degree ----------------
__global__ void zero_deg_kernel(unsigned* __restrict__ deg, int N) {
    int i = blockIdx.x * blockDim.x + threadIdx.x;
    if (i < N) deg[i] = 0u;
}

// ---------------- degree: deg[dst] += 1 (int atomics) ----------------
__global__ void degree_kernel(const int* __restrict__ dst, unsigned* __restrict__ deg, int E) {
    int stride = gridDim.x * blockDim.x;
    for (int e = blockIdx.x * blockDim.x + threadIdx.x; e < E; e += stride)
        atomicAdd(&deg[dst[e]], 1u);
}

// ---------------- scan phase A: per-block sums of 1024 degrees ----------------
__global__ void scan_blocksum_kernel(const unsigned* __restrict__ deg,
                                     unsigned* __restrict__ bsum, int N) {
    __shared__ unsigned s[256];
    int tid = threadIdx.x;
    int base = blockIdx.x * SCAN_ELEMS + tid * 4;
    unsigned t = 0;
    if (base < N) {  // N%4==0 so base<N implies base+3<N
        uint4 v = *reinterpret_cast<const uint4*>(deg + base);
        t = v.x + v.y + v.z + v.w;
    }
    s[tid] = t; __syncthreads();
    for (int off = 128; off > 0; off >>= 1) {
        if (tid < off) s[tid] += s[tid + off];
        __syncthreads();
    }
    if (tid == 0) bsum[blockIdx.x] = s[0];
}

// ---------------- scan phase B: exclusive scan of 489 partials (1 block) ------
__global__ void scan_partials_kernel(const unsigned* __restrict__ bsum,
                                     unsigned* __restrict__ boff,
                                     unsigned* __restrict__ rowstart, int nb) {
    __shared__ unsigned s[512];
    int tid = threadIdx.x;
    unsigned v = (tid < nb) ? bsum[tid] : 0u;
    s[tid] = v; __syncthreads();
    for (int off = 1; off < 512; off <<= 1) {
        unsigned a = (tid >= off) ? s[tid - off] : 0u;
        __syncthreads();
        s[tid] += a; __syncthreads();
    }
    if (tid < nb) boff[tid] = s[tid] - v;  // exclusive
    if (tid == 0) rowstart[N_NODES] = (unsigned)N_EDGES;
}

// ---------------- scan phase C: apply — rowstart/cursor/dinv + prescale x ------
__global__ void scan_apply_kernel(const unsigned* __restrict__ deg,
                                  const unsigned* __restrict__ boff,
                                  unsigned* __restrict__ rowstart,
                                  unsigned* __restrict__ cursor,
                                  float* __restrict__ dinv, float* x, int N) {
    __shared__ unsigned s[256];
    int tid = threadIdx.x;
    int base = blockIdx.x * SCAN_ELEMS + tid * 4;
    uint4 d = make_uint4(0u, 0u, 0u, 0u);
    if (base < N) d = *reinterpret_cast<const uint4*>(deg + base);
    unsigned tsum = d.x + d.y + d.z + d.w;
    s[tid] = tsum; __syncthreads();
    for (int off = 1; off < 256; off <<= 1) {
        unsigned a = (tid >= off) ? s[tid - off] : 0u;
        __syncthreads();
        s[tid] += a; __syncthreads();
    }
    unsigned run = s[tid] - tsum + boff[blockIdx.x];
    if (base < N) {
        unsigned dd[4] = {d.x, d.y, d.z, d.w};
        #pragma unroll
        for (int k = 0; k < 4; ++k) {
            int i = base + k;
            rowstart[i] = run;
            cursor[i] = run;
            run += dd[k];
            float di = rsqrtf((float)dd[k] + 1.0f);  // +1 = self-loop
            dinv[i] = di;
            float2* xr = reinterpret_cast<float2*>(x + (size_t)i * IN_DIM);
            #pragma unroll
            for (int q = 0; q < 5; ++q) {
                float2 t = xr[q]; t.x *= di; t.y *= di; xr[q] = t;
            }
        }
    }
}

// ---------------- scatter: fill CSR adjacency (src indices grouped by dst) ----
__global__ void scatter_kernel(const int* __restrict__ src, const int* __restrict__ dst,
                               unsigned* __restrict__ cursor, int* __restrict__ csr, int E) {
    int stride = gridDim.x * blockDim.x;
    for (int e = blockIdx.x * blockDim.x + threadIdx.x; e < E; e += stride) {
        int d = dst[e];
        unsigned pos = atomicAdd(&cursor[d], 1u);
        csr[pos] = src[e];
    }
}

// ---------------- fused: layer-1 gather + MLP transform + layer-2 prescale ----
// v = dinv[i] * (sum_{s in N(i)} xs[s] + xs[i]);  xs = x*dinv (prescaled)
// h = relu(v@W1+b1);  ts[i] = dinv[i] * (h@W2)
__global__ void gather1_kernel(const int* __restrict__ csr, const unsigned* __restrict__ rowstart,
                               const float* __restrict__ xs, const float* __restrict__ dinv,
                               const float* __restrict__ W1, const float* __restrict__ b1,
                               const float* __restrict__ W2,
                               float2* __restrict__ ts, int N) {
    __shared__ float sW1[IN_DIM * HID_DIM];
    __shared__ float sb1[HID_DIM];
    __shared__ float sW2[HID_DIM * OUT_DIM];
    for (int k = threadIdx.x; k < IN_DIM * HID_DIM; k += blockDim.x) sW1[k] = W1[k];
    for (int k = threadIdx.x; k < HID_DIM; k += blockDim.x) sb1[k] = b1[k];
    for (int k = threadIdx.x; k < HID_DIM * OUT_DIM; k += blockDim.x) sW2[k] = W2[k];
    __syncthreads();

    int i = blockIdx.x * blockDim.x + threadIdx.x;
    if (i >= N) return;
    unsigned beg = rowstart[i], end = rowstart[i + 1];
    float v[IN_DIM];
    const float2* xi = reinterpret_cast<const float2*>(xs + (size_t)i * IN_DIM);
    #pragma unroll
    for (int q = 0; q < 5; ++q) { float2 t = xi[q]; v[2*q] = t.x; v[2*q+1] = t.y; }
    for (unsigned e = beg; e < end; ++e) {
        int s = csr[e];
        const float2* xr = reinterpret_cast<const float2*>(xs + (size_t)s * IN_DIM);
        #pragma unroll
        for (int q = 0; q < 5; ++q) { float2 t = xr[q]; v[2*q] += t.x; v[2*q+1] += t.y; }
    }
    float di = dinv[i];
    #pragma unroll
    for (int k = 0; k < IN_DIM; ++k) v[k] *= di;
    float t0 = 0.0f, t1 = 0.0f;
    #pragma unroll
    for (int j = 0; j < HID_DIM; ++j) {
        float h = sb1[j];
        #pragma unroll
        for (int k = 0; k < IN_DIM; ++k) h = fmaf(v[k], sW1[k * HID_DIM + j], h);
        h = fmaxf(h, 0.0f);
        t0 = fmaf(h, sW2[2 * j + 0], t0);
        t1 = fmaf(h, sW2[2 * j + 1], t1);
    }
    ts[i] = make_float2(t0 * di, t1 * di);
}

// ---------------- fused: layer-2 gather + bias + log_softmax ----------------
__global__ void gather2_kernel(const int* __restrict__ csr, const unsigned* __restrict__ rowstart,
                               const float2* __restrict__ ts, const float* __restrict__ dinv,
                               const float* __restrict__ b2, float2* __restrict__ out, int N) {
    int i = blockIdx.x * blockDim.x + threadIdx.x;
    if (i >= N) return;
    unsigned beg = rowstart[i], end = rowstart[i + 1];
    float2 acc = ts[i];  // self-loop
    for (unsigned e = beg; e < end; ++e) {
        float2 t = ts[csr[e]];
        acc.x += t.x; acc.y += t.y;
    }
    float di = dinv[i];
    float a0 = di * acc.x + b2[0];
    float a1 = di * acc.y + b2[1];
    float m = fmaxf(a0, a1);
    float lse = m + logf(expf(a0 - m) + expf(a1 - m));
    out[i] = make_float2(a0 - lse, a1 - lse);
}

extern "C" void kernel_launch(void* const* d_in, const int* in_sizes, int n_in,
                              void* d_out, int out_size, void* d_ws, size_t ws_size,
                              hipStream_t stream) {
    float* x        = (float*)d_in[0];       // prescaled in place (harness restores)
    const int* ei   = (const int*)d_in[1];   // [2, E]: src row then dst row
    const float* W1 = (const float*)d_in[2];
    const float* b1 = (const float*)d_in[3];
    const float* W2 = (const float*)d_in[4];
    const float* b2 = (const float*)d_in[5];
    float2* out = (float2*)d_out;

    const int* src = ei;
    const int* dst = ei + N_EDGES;

    // workspace (4B elems):
    // deg[N] | rowstart[N+8] | cursor[N] | bsum[512] | boff[512] | dinv[N] | csr[E] | ts[2N]
    unsigned* deg      = (unsigned*)d_ws;
    unsigned* rowstart = deg + N_NODES;
    unsigned* cursor   = rowstart + N_NODES + 8;
    unsigned* bsum     = cursor + N_NODES;
    unsigned* boff     = bsum + 512;
    float*    dinv     = (float*)(boff + 512);
    int*      csr      = (int*)(dinv + N_NODES);
    float2*   ts       = (float2*)(csr + N_EDGES);

    const int BLK = 256;
    const int node_grid = (N_NODES + BLK - 1) / BLK;  // 1954
    const int edge_grid = 8192;

    zero_deg_kernel<<<node_grid, BLK, 0, stream>>>(deg, N_NODES);
    degree_kernel<<<edge_grid, BLK, 0, stream>>>(dst, deg, N_EDGES);
    scan_blocksum_kernel<<<NBLK_SCAN, BLK, 0, stream>>>(deg, bsum, N_NODES);
    scan_partials_kernel<<<1, 512, 0, stream>>>(bsum, boff, rowstart, NBLK_SCAN);
    scan_apply_kernel<<<NBLK_SCAN, BLK, 0, stream>>>(deg, boff, rowstart, cursor, dinv, x, N_NODES);
    scatter_kernel<<<edge_grid, BLK, 0, stream>>>(src, dst, cursor, csr, N_EDGES);
    gather1_kernel<<<node_grid, BLK, 0, stream>>>(csr, rowstart, x, dinv, W1, b1, W2, ts, N_NODES);
    gather2_kernel<<<node_grid, BLK, 0, stream>>>(csr, rowstart, ts, dinv, b2, out, N_NODES);
}

// Round 5
// 904.088 us; speedup vs baseline: 5.9732x; 1.4665x over previous
//
#include <hip/hip_runtime.h>
#include <math.h>

constexpr int N_NODES = 500000;
constexpr int N_EDGES = 8000000;
constexpr int IN_DIM = 10, HID_DIM = 35, OUT_DIM = 2;

constexpr int BUCKET_BITS = 11;                       // 2048 nodes per bucket
constexpr int BNODES = 1 << BUCKET_BITS;              // 2048
constexpr int NB = (N_NODES + BNODES - 1) / BNODES;   // 245 buckets
constexpr int NBP = 256;                              // padded bucket-array size

constexpr int PART_TPB = 1024;
constexpr int EPT = 16;                               // edges per thread in partition
constexpr int TILE = PART_TPB * EPT;                  // 16384
constexpr int NTILES = (N_EDGES + TILE - 1) / TILE;   // 489

// HW f32 atomic (global_atomic_add_f32 / ds_add_f32); O(1) values, denormal
// semantics irrelevant at our tolerance.
__device__ __forceinline__ void atomAddF(float* p, float v) { unsafeAtomicAdd(p, v); }

// ---------------- zero the bucket counters ----------------
__global__ void zero_small_kernel(unsigned* __restrict__ bcount) {
    bcount[threadIdx.x] = 0u;
}

// ---------------- coarse histogram: edges per dst-bucket ----------------
__global__ void hist_kernel(const int* __restrict__ dst, unsigned* __restrict__ bcount, int E) {
    __shared__ unsigned h[NBP];
    for (int k = threadIdx.x; k < NBP; k += blockDim.x) h[k] = 0u;
    __syncthreads();
    int stride = gridDim.x * blockDim.x;
    for (int e = blockIdx.x * blockDim.x + threadIdx.x; e < E; e += stride)
        atomicAdd(&h[dst[e] >> BUCKET_BITS], 1u);
    __syncthreads();
    for (int k = threadIdx.x; k < NB; k += blockDim.x)
        if (h[k]) atomicAdd(&bcount[k], h[k]);
}

// ---------------- exclusive scan of 245 bucket counts (1 block) ----------------
__global__ void scan_kernel(const unsigned* __restrict__ bcount,
                            unsigned* __restrict__ bbase, unsigned* __restrict__ bcursor) {
    __shared__ unsigned s[NBP];
    int t = threadIdx.x;
    unsigned v = (t < NB) ? bcount[t] : 0u;
    s[t] = v; __syncthreads();
    for (int off = 1; off < NBP; off <<= 1) {
        unsigned a = (t >= off) ? s[t - off] : 0u;
        __syncthreads();
        s[t] += a;
        __syncthreads();
    }
    if (t < NB) { bbase[t] = s[t] - v; bcursor[t] = s[t] - v; }
    if (t == 0) bbase[NB] = (unsigned)N_EDGES;
}

// ---------------- partition: pack (src<<11 | dst&2047) into bucket regions ----
__global__ __launch_bounds__(PART_TPB) void partition_kernel(
        const int* __restrict__ src, const int* __restrict__ dst,
        unsigned* __restrict__ bcursor, unsigned* __restrict__ packed, int E) {
    __shared__ unsigned h[NBP], base[NBP], c2[NBP];
    int t = threadIdx.x;
    for (int k = t; k < NBP; k += PART_TPB) { h[k] = 0u; c2[k] = 0u; }
    __syncthreads();
    int tile0 = blockIdx.x * TILE;
    int d[EPT];
    #pragma unroll
    for (int q = 0; q < EPT; ++q) {
        int e = tile0 + q * PART_TPB + t;
        d[q] = (e < E) ? dst[e] : -1;
        if (d[q] >= 0) atomicAdd(&h[d[q] >> BUCKET_BITS], 1u);
    }
    __syncthreads();
    for (int k = t; k < NB; k += PART_TPB)
        if (h[k]) base[k] = atomicAdd(&bcursor[k], h[k]);
    __syncthreads();
    #pragma unroll
    for (int q = 0; q < EPT; ++q) {
        int e = tile0 + q * PART_TPB + t;
        if (d[q] >= 0) {
            int b = d[q] >> BUCKET_BITS;
            unsigned pos = base[b] + atomicAdd(&c2[b], 1u);
            packed[pos] = ((unsigned)src[e] << BUCKET_BITS) | (unsigned)(d[q] & (BNODES - 1));
        }
    }
}

// ---------------- per-bucket: degree -> dinv, prescale x in place ----------------
__global__ __launch_bounds__(1024) void deg_kernel(
        const unsigned* __restrict__ packed, const unsigned* __restrict__ bbase,
        float* __restrict__ dinv, float* __restrict__ x, int N) {
    __shared__ unsigned cnt[BNODES];
    int b = blockIdx.x, t = threadIdx.x;
    for (int k = t; k < BNODES; k += 1024) cnt[k] = 0u;
    __syncthreads();
    unsigned beg = bbase[b], end = bbase[b + 1];
    for (unsigned e = beg + t; e < end; e += 1024)
        atomicAdd(&cnt[packed[e] & (BNODES - 1)], 1u);
    __syncthreads();
    int node0 = b << BUCKET_BITS;
    for (int k = t; k < BNODES; k += 1024) {
        int i = node0 + k;
        if (i >= N) continue;
        float di = rsqrtf((float)cnt[k] + 1.0f);  // +1 = self-loop
        dinv[i] = di;
        float2* xr = reinterpret_cast<float2*>(x + (size_t)i * IN_DIM);
        #pragma unroll
        for (int q = 0; q < 5; ++q) { float2 v = xr[q]; v.x *= di; v.y *= di; xr[q] = v; }
    }
}

// ---------------- per-bucket layer-1: LDS-accumulate + fused MLP ----------------
// acc[dl] = sum xs[src]; v = dinv*(acc + xs[i]); h = relu(v@W1+b1); ts = dinv*(h@W2)
__global__ __launch_bounds__(1024) void agg1_kernel(
        const unsigned* __restrict__ packed, const unsigned* __restrict__ bbase,
        const float* __restrict__ xs, const float* __restrict__ dinv,
        const float* __restrict__ W1, const float* __restrict__ b1,
        const float* __restrict__ W2, float2* __restrict__ ts, int N) {
    __shared__ float acc[BNODES * IN_DIM];  // 80 KB
    __shared__ float sW1[IN_DIM * HID_DIM];
    __shared__ float sb1[HID_DIM];
    __shared__ float sW2[HID_DIM * OUT_DIM];
    int b = blockIdx.x, t = threadIdx.x;
    for (int k = t; k < BNODES * IN_DIM; k += 1024) acc[k] = 0.0f;
    for (int k = t; k < IN_DIM * HID_DIM; k += 1024) sW1[k] = W1[k];
    if (t < HID_DIM) sb1[t] = b1[t];
    if (t < HID_DIM * OUT_DIM) sW2[t] = W2[t];
    __syncthreads();
    unsigned beg = bbase[b], end = bbase[b + 1];
    for (unsigned e = beg + t; e < end; e += 1024) {
        unsigned p = packed[e];
        const float2* xr = reinterpret_cast<const float2*>(xs + (size_t)(p >> BUCKET_BITS) * IN_DIM);
        float* a = acc + (p & (BNODES - 1)) * IN_DIM;
        #pragma unroll
        for (int q = 0; q < 5; ++q) {
            float2 v = xr[q];
            atomAddF(a + 2 * q + 0, v.x);
            atomAddF(a + 2 * q + 1, v.y);
        }
    }
    __syncthreads();
    int node0 = b << BUCKET_BITS;
    for (int k = t; k < BNODES; k += 1024) {
        int i = node0 + k;
        if (i >= N) continue;
        float di = dinv[i];
        const float2* xi = reinterpret_cast<const float2*>(xs + (size_t)i * IN_DIM);
        float v[IN_DIM];
        #pragma unroll
        for (int q = 0; q < 5; ++q) {
            float2 xv = xi[q];
            v[2*q+0] = di * (acc[k * IN_DIM + 2*q+0] + xv.x);
            v[2*q+1] = di * (acc[k * IN_DIM + 2*q+1] + xv.y);
        }
        float t0 = 0.0f, t1 = 0.0f;
        #pragma unroll
        for (int j = 0; j < HID_DIM; ++j) {
            float hh = sb1[j];
            #pragma unroll
            for (int q = 0; q < IN_DIM; ++q) hh = fmaf(v[q], sW1[q * HID_DIM + j], hh);
            hh = fmaxf(hh, 0.0f);
            t0 = fmaf(hh, sW2[2*j+0], t0);
            t1 = fmaf(hh, sW2[2*j+1], t1);
        }
        ts[i] = make_float2(t0 * di, t1 * di);
    }
}

// ---------------- per-bucket layer-2: LDS-accumulate + log_softmax ----------------
__global__ __launch_bounds__(1024) void agg2_kernel(
        const unsigned* __restrict__ packed, const unsigned* __restrict__ bbase,
        const float2* __restrict__ ts, const float* __restrict__ dinv,
        const float* __restrict__ b2, float2* __restrict__ out, int N) {
    __shared__ float acc[BNODES * 2];  // 16 KB
    int b = blockIdx.x, t = threadIdx.x;
    for (int k = t; k < BNODES * 2; k += 1024) acc[k] = 0.0f;
    __syncthreads();
    unsigned beg = bbase[b], end = bbase[b + 1];
    for (unsigned e = beg + t; e < end; e += 1024) {
        unsigned p = packed[e];
        float2 tv = ts[p >> BUCKET_BITS];
        unsigned dl = p & (BNODES - 1);
        atomAddF(&acc[dl * 2 + 0], tv.x);
        atomAddF(&acc[dl * 2 + 1], tv.y);
    }
    __syncthreads();
    float b20 = b2[0], b21 = b2[1];
    int node0 = b << BUCKET_BITS;
    for (int k = t; k < BNODES; k += 1024) {
        int i = node0 + k;
        if (i >= N) continue;
        float di = dinv[i];
        float2 tv = ts[i];  // self-loop (ts already has dinv[i] factor)
        float a0 = di * (acc[k*2+0] + tv.x) + b20;
        float a1 = di * (acc[k*2+1] + tv.y) + b21;
        float m = fmaxf(a0, a1);
        float lse = m + logf(expf(a0 - m) + expf(a1 - m));
        out[i] = make_float2(a0 - lse, a1 - lse);
    }
}

extern "C" void kernel_launch(void* const* d_in, const int* in_sizes, int n_in,
                              void* d_out, int out_size, void* d_ws, size_t ws_size,
                              hipStream_t stream) {
    float* x        = (float*)d_in[0];       // prescaled in place (harness restores)
    const int* ei   = (const int*)d_in[1];   // [2, E]: src row then dst row
    const float* W1 = (const float*)d_in[2];
    const float* b1 = (const float*)d_in[3];
    const float* W2 = (const float*)d_in[4];
    const float* b2 = (const float*)d_in[5];
    float2* out = (float2*)d_out;

    const int* src = ei;
    const int* dst = ei + N_EDGES;

    // workspace (4B elems):
    // bcount[256] | bbase[257] | bcursor[256] | dinv[N] | ts[2N] | packed[E]   ~= 38 MB
    unsigned* bcount  = (unsigned*)d_ws;
    unsigned* bbase   = bcount + NBP;
    unsigned* bcursor = bbase + NBP + 1;
    float*    dinv    = (float*)(bcursor + NBP);
    float2*   ts      = (float2*)(dinv + N_NODES);
    unsigned* packed  = (unsigned*)(ts + N_NODES);

    zero_small_kernel<<<1, NBP, 0, stream>>>(bcount);
    hist_kernel<<<1024, 256, 0, stream>>>(dst, bcount, N_EDGES);
    scan_kernel<<<1, NBP, 0, stream>>>(bcount, bbase, bcursor);
    partition_kernel<<<NTILES, PART_TPB, 0, stream>>>(src, dst, bcursor, packed, N_EDGES);
    deg_kernel<<<NB, 1024, 0, stream>>>(packed, bbase, dinv, x, N_NODES);
    agg1_kernel<<<NB, 1024, 0, stream>>>(packed, bbase, x, dinv, W1, b1, W2, ts, N_NODES);
    agg2_kernel<<<NB, 1024, 0, stream>>>(packed, bbase, ts, dinv, b2, out, N_NODES);
}